// Round 3
// baseline (288.063 us; speedup 1.0000x reference)
//
#include <hip/hip_runtime.h>
#include <hip/hip_bf16.h>
#include <stdint.h>

#define G_    128
#define NP_   1024
#define F_    16
#define K_    16
#define H_    64
#define L_    64
#define OUT_  128

#define SLAB    32
#define DSTRIDE 68            // floats; (4j+lane)%32 -> 2 lanes/bank (free)
#define JQ_     4             // j-range split factor
#define JLEN    (NP_ / JQ_)   // 256 j per block
#define NSLABQ  (JLEN / SLAB) // 8 slabs per block

typedef short  short8v  __attribute__((ext_vector_type(8)));
typedef short  short4v  __attribute__((ext_vector_type(4)));
typedef float  float4v  __attribute__((ext_vector_type(4)));

__device__ __forceinline__ uint16_t bf_rne(float f) {
    uint32_t u = __float_as_uint(f);
    return (uint16_t)((u + 0x7FFFu + ((u >> 16) & 1u)) >> 16);
}
__device__ __forceinline__ float bf_to_f(uint16_t h) {
    return __uint_as_float((uint32_t)h << 16);
}

// ---------------------------------------------------------------------------
// Kernel A: per-point u/v tables (unchanged).
// ---------------------------------------------------------------------------
__global__ __launch_bounds__(256) void uv_kernel(
    const float* __restrict__ x, const float* __restrict__ W1,
    const float* __restrict__ b1, float* __restrict__ u, float* __restrict__ v)
{
    const int lane = threadIdx.x & 63;
    const int wave = threadIdx.x >> 6;

    float wb[16], wd[16];
#pragma unroll
    for (int f = 0; f < 16; ++f) {
        float wt  = W1[f * 64 + lane];
        float wbo = W1[(16 + f) * 64 + lane];
        wb[f] = wbo;
        wd[f] = wt - wbo;
    }
    const float bias = b1[lane];

    const int base = blockIdx.x * 64 + wave * 16;
    for (int n = 0; n < 16; ++n) {
        const int p = base + n;
        const float4* xr = (const float4*)(x + (size_t)p * 16);
        float4 a0 = xr[0], a1 = xr[1], a2 = xr[2], a3 = xr[3];
        float xv[16] = {a0.x,a0.y,a0.z,a0.w, a1.x,a1.y,a1.z,a1.w,
                        a2.x,a2.y,a2.z,a2.w, a3.x,a3.y,a3.z,a3.w};
        float uu = bias, vv = 0.f;
#pragma unroll
        for (int f = 0; f < 16; ++f) {
            uu = fmaf(xv[f], wd[f], uu);
            vv = fmaf(xv[f], wb[f], vv);
        }
        u[(size_t)p * 64 + lane] = uu;
        v[(size_t)p * 64 + lane] = vv;
    }
}

// ---------------------------------------------------------------------------
// Kernel B: kNN quarter-scan via MFMA distance tiles.
// Block = 256 threads = 4 waves = 256 queries x 256-j quarter.
// grid = G*4(qchunk)*4(jq) = 2048 -> 4 blocks/CU (LDS 38.9KB) = 4 waves/SIMD.
// Scan is BRANCHLESS: med3 chain is a no-op when d >= hp[15].
// Partial top-16 stored as packed floats (low 8 bits = local j).
// ---------------------------------------------------------------------------
__global__ __launch_bounds__(256, 4) void knn_kernel(
    const float* __restrict__ x, float* __restrict__ part)
{
    __shared__ float    DT[4][SLAB * DSTRIDE];  // 34816 B (per-wave private)
    __shared__ uint16_t zh[SLAB * 24];
    __shared__ uint16_t zl[SLAB * 24];
    __shared__ float    sqs[JLEN];              // 1 KB

    const int b      = blockIdx.x;
    const int g      = b >> 4;
    const int qchunk = (b >> 2) & 3;
    const int jq     = b & 3;
    const float* xg  = x + (size_t)g * NP_ * F_;
    const int tid  = threadIdx.x;
    const int lane = tid & 63;
    const int wave = tid >> 6;

    // --- sq_j for this block's j-quarter (exact fp32), one row per thread ---
    {
        const float4* p = (const float4*)(xg + (size_t)(jq * JLEN + tid) * 16);
        float4 a = p[0], bb = p[1], c = p[2], d = p[3];
        float s = a.x*a.x + a.y*a.y + a.z*a.z + a.w*a.w;
        s += bb.x*bb.x + bb.y*bb.y + bb.z*bb.z + bb.w*bb.w;
        s += c.x*c.x + c.y*c.y + c.z*c.z + c.w*c.w;
        s += d.x*d.x + d.y*d.y + d.z*d.z + d.w*d.w;
        sqs[tid] = s;
    }

    // --- A fragments: wave's 64 query rows, 4 row-tiles of 16 ---
    const int qbase = qchunk * 256 + wave * 64;
    const int arow  = lane & 15;
    const int agrp  = lane >> 4;
    const int aoct  = agrp & 1;
    short8v a1[4], a2[4];
#pragma unroll
    for (int rt = 0; rt < 4; ++rt) {
        const float* src = xg + (size_t)(qbase + rt * 16 + arow) * 16 + aoct * 8;
        float4 f0 = ((const float4*)src)[0];
        float4 f1 = ((const float4*)src)[1];
        float fv[8] = {f0.x,f0.y,f0.z,f0.w, f1.x,f1.y,f1.z,f1.w};
        short8v h, l;
#pragma unroll
        for (int i = 0; i < 8; ++i) {
            uint16_t hb = bf_rne(fv[i]);
            h[i] = (short)hb;
            l[i] = (short)bf_rne(fv[i] - bf_to_f(hb));
        }
        short8v zz = {0,0,0,0,0,0,0,0};
        a1[rt] = (agrp < 2) ? h : l;
        a2[rt] = (agrp < 2) ? h : zz;
    }

    float hp[16];
#pragma unroll
    for (int m = 0; m < 16; ++m) hp[m] = __uint_as_float(0x7F000000u);

    float* dtw = DT[wave];
    const int bcol  = lane & 15;
    const int bgrp4 = (lane >> 4) & 1;

#pragma unroll
    for (int sl = 0; sl < NSLABQ; ++sl) {
        __syncthreads();
        // --- stage slab rows as bf16 hi/lo (32 rows x 4 quads) ---
        if (tid < SLAB * 4) {
            const int row = tid >> 2, q4 = tid & 3;
            const float4 f = *(const float4*)(
                xg + (size_t)(jq * JLEN + sl * SLAB + row) * 16 + q4 * 4);
            uint16_t h0 = bf_rne(f.x), h1 = bf_rne(f.y), h2 = bf_rne(f.z), h3 = bf_rne(f.w);
            short4v hv = {(short)h0, (short)h1, (short)h2, (short)h3};
            short4v lv = {(short)bf_rne(f.x - bf_to_f(h0)), (short)bf_rne(f.y - bf_to_f(h1)),
                          (short)bf_rne(f.z - bf_to_f(h2)), (short)bf_rne(f.w - bf_to_f(h3))};
            *(short4v*)&zh[row * 24 + q4 * 4] = hv;
            *(short4v*)&zl[row * 24 + q4 * 4] = lv;
        }
        __syncthreads();

        // --- MFMA distance tiles + fold + transpose-store to DT ---
#pragma unroll
        for (int ct = 0; ct < SLAB / 16; ++ct) {
            short8v b1v = *(const short8v*)&zh[(ct * 16 + bcol) * 24 + bgrp4 * 8];
            short8v b2v = *(const short8v*)&zl[(ct * 16 + bcol) * 24 + bgrp4 * 8];
            const float sqv = sqs[sl * SLAB + ct * 16 + bcol];
#pragma unroll
            for (int rt = 0; rt < 4; ++rt) {
                float4v acc = {0.f, 0.f, 0.f, 0.f};
                acc = __builtin_amdgcn_mfma_f32_16x16x32_bf16(a1[rt], b1v, acc, 0, 0, 0);
                acc = __builtin_amdgcn_mfma_f32_16x16x32_bf16(a2[rt], b2v, acc, 0, 0, 0);
                float4 outv;
                outv.x = fmaf(-2.f, acc[0], sqv);
                outv.y = fmaf(-2.f, acc[1], sqv);
                outv.z = fmaf(-2.f, acc[2], sqv);
                outv.w = fmaf(-2.f, acc[3], sqv);
                *(float4*)&dtw[(ct * 16 + bcol) * DSTRIDE + rt * 16 + (lane >> 4) * 4] = outv;
            }
        }
        asm volatile("s_waitcnt lgkmcnt(0)" ::: "memory");
        __builtin_amdgcn_sched_barrier(0);

        // --- branchless scan: lane owns query (qbase+lane) ---
        const float* dtr = dtw + lane;
#pragma unroll
        for (int j = 0; j < SLAB; ++j) {
            float d = dtr[j * DSTRIDE];
            const uint32_t jl = (uint32_t)(sl * SLAB + j);   // compile-time
            float dpf = __uint_as_float(
                (__float_as_uint(d) & 0xFFFFFF00u) | jl);
#pragma unroll
            for (int m = 15; m >= 1; --m)
                hp[m] = __builtin_amdgcn_fmed3f(dpf, hp[m - 1], hp[m]);
            hp[0] = fminf(hp[0], dpf);
        }
    }

    // --- store packed partial list: part[qglobal*64 + jq*16 + m] ---
    const size_t qg = (size_t)g * NP_ + qchunk * 256 + wave * 64 + lane;
    float* dst = part + qg * 64 + jq * 16;
#pragma unroll
    for (int m4 = 0; m4 < 4; ++m4) {
        float4 o = {hp[m4*4+0], hp[m4*4+1], hp[m4*4+2], hp[m4*4+3]};
        *(float4*)(dst + m4 * 4) = o;
    }
}

// ---------------------------------------------------------------------------
// Kernel B2: merge 4 quarter-wise top-16 lists -> global top-16 per query.
// Thread per query; 64 branchless chain-inserts. Quarter id folded into
// bits 8-9 (global j = bits 0..9).
// ---------------------------------------------------------------------------
__global__ __launch_bounds__(256) void merge_kernel(
    const float* __restrict__ part, int* __restrict__ idxw)
{
    const size_t p = (size_t)blockIdx.x * 256 + threadIdx.x;
    const float* src = part + p * 64;

    float hp[16];
#pragma unroll
    for (int m = 0; m < 16; ++m) hp[m] = __uint_as_float(0x7F000000u);

#pragma unroll
    for (int qtr = 0; qtr < 4; ++qtr) {
#pragma unroll
        for (int m4 = 0; m4 < 4; ++m4) {
            float4 v = *(const float4*)(src + qtr * 16 + m4 * 4);
            float e[4] = {v.x, v.y, v.z, v.w};
#pragma unroll
            for (int t = 0; t < 4; ++t) {
                uint32_t uu = __float_as_uint(e[t]);
                float key = __uint_as_float(
                    (uu & 0xFFFFFC00u) | ((uint32_t)qtr << 8) | (uu & 0xFFu));
#pragma unroll
                for (int m = 15; m >= 1; --m)
                    hp[m] = __builtin_amdgcn_fmed3f(key, hp[m - 1], hp[m]);
                hp[0] = fminf(hp[0], key);
            }
        }
    }

    int* row = idxw + p * K_;
#pragma unroll
    for (int m = 0; m < 16; ++m)
        row[m] = (int)(__float_as_uint(hp[m]) & 1023u);
}

// ---------------------------------------------------------------------------
// Kernel C: S[g][h] = sum_{i,k} relu(u_i[h] + v_{idx[i][k]}[h])  (unchanged)
// ---------------------------------------------------------------------------
__global__ __launch_bounds__(256) void gather_kernel(
    const float* __restrict__ u, const float* __restrict__ v,
    const int* __restrict__ idxw, float* __restrict__ S)
{
    const int lane = threadIdx.x & 63;
    const int wave = threadIdx.x >> 6;
    const int pbase = blockIdx.x * 128 + wave * 32;
    const int g = pbase >> 10;
    const float* vg = v + (((size_t)g << 10) << 6);
    float acc = 0.f;
    for (int n = 0; n < 32; ++n) {
        const int ii = pbase + n;
        const float uu = u[(size_t)ii * 64 + lane];
        const int4* irow = (const int4*)(idxw + (size_t)ii * 16);
#pragma unroll
        for (int q = 0; q < 4; ++q) {
            int4 j4 = irow[q];
            float v0 = vg[(size_t)j4.x * 64 + lane];
            float v1 = vg[(size_t)j4.y * 64 + lane];
            float v2 = vg[(size_t)j4.z * 64 + lane];
            float v3 = vg[(size_t)j4.w * 64 + lane];
            acc += fmaxf(0.f, uu + v0);
            acc += fmaxf(0.f, uu + v1);
            acc += fmaxf(0.f, uu + v2);
            acc += fmaxf(0.f, uu + v3);
        }
    }
    atomicAdd(&S[(g << 6) + lane], acc);
}

// ---------------------------------------------------------------------------
// Kernel D: per-group head (unchanged).
// ---------------------------------------------------------------------------
__global__ __launch_bounds__(128) void head_kernel(
    const float* __restrict__ S, const float* __restrict__ W2,
    const float* __restrict__ b2, const float* __restrict__ Wf,
    const float* __restrict__ bf, float* __restrict__ out)
{
    __shared__ float hbar[64];
    __shared__ float t[64];
    const int g = blockIdx.x;
    const int tid = threadIdx.x;
    if (tid < 64) hbar[tid] = S[g * 64 + tid] * (1.f / (1024.f * 16.f));
    __syncthreads();
    if (tid < 64) {
        float a = b2[tid];
        for (int h = 0; h < 64; ++h) a = fmaf(hbar[h], W2[h * 64 + tid], a);
        t[tid] = a;
    }
    __syncthreads();
    float a = bf[tid];
    for (int h = 0; h < 64; ++h) a = fmaf(t[h], Wf[h * 128 + tid], a);
    out[g * 128 + tid] = a;
}

// ---------------------------------------------------------------------------
extern "C" void kernel_launch(void* const* d_in, const int* in_sizes, int n_in,
                              void* d_out, int out_size, void* d_ws, size_t ws_size,
                              hipStream_t stream)
{
    const float* x  = (const float*)d_in[0];
    const float* W1 = (const float*)d_in[2];
    const float* b1 = (const float*)d_in[3];
    const float* W2 = (const float*)d_in[4];
    const float* b2 = (const float*)d_in[5];
    const float* Wf = (const float*)d_in[6];
    const float* bf = (const float*)d_in[7];
    float* out = (float*)d_out;

    char* ws = (char*)d_ws;
    const size_t N = (size_t)G_ * NP_;               // 131072
    float* u    = (float*)ws;                        // 32 MB
    float* v    = (float*)(ws + N * 64 * 4);         // 32 MB
    int*   idxw = (int*)  (ws + 2 * N * 64 * 4);     //  8 MB
    float* S    = (float*)(ws + 2 * N * 64 * 4 + N * 16 * 4);
    float* part = u;   // aliases u: lifetime (knn->merge) ends before uv writes u

    hipMemsetAsync(S, 0, G_ * H_ * sizeof(float), stream);

    knn_kernel   <<<G_ * 16, 256, 0, stream>>>(x, part);
    merge_kernel <<<(G_ * NP_) / 256, 256, 0, stream>>>(part, idxw);
    uv_kernel    <<<2048, 256, 0, stream>>>(x, W1, b1, u, v);
    gather_kernel<<<1024, 256, 0, stream>>>(u, v, idxw, S);
    head_kernel  <<<G_, 128, 0, stream>>>(S, W2, b2, Wf, bf, out);
}

// Round 4
// 287.129 us; speedup vs baseline: 1.0033x; 1.0033x over previous
//
#include <hip/hip_runtime.h>
#include <hip/hip_bf16.h>
#include <stdint.h>

#define G_    128
#define NP_   1024
#define F_    16
#define K_    16
#define H_    64
#define L_    64
#define OUT_  128

#define SLAB    32
#define DSTRIDE 68            // floats; (4j+lane)%32 -> 2 lanes/bank (free)
#define JQ_     4             // j-range split factor
#define JLEN    (NP_ / JQ_)   // 256 j per block
#define NSLABQ  (JLEN / SLAB) // 8 slabs per block

typedef short  short8v  __attribute__((ext_vector_type(8)));
typedef short  short4v  __attribute__((ext_vector_type(4)));
typedef float  float4v  __attribute__((ext_vector_type(4)));

__device__ __forceinline__ uint16_t bf_rne(float f) {
    uint32_t u = __float_as_uint(f);
    return (uint16_t)((u + 0x7FFFu + ((u >> 16) & 1u)) >> 16);
}
__device__ __forceinline__ float bf_to_f(uint16_t h) {
    return __uint_as_float((uint32_t)h << 16);
}

// ---------------------------------------------------------------------------
// Kernel A: per-point u/v tables (unchanged).
// ---------------------------------------------------------------------------
__global__ __launch_bounds__(256) void uv_kernel(
    const float* __restrict__ x, const float* __restrict__ W1,
    const float* __restrict__ b1, float* __restrict__ u, float* __restrict__ v)
{
    const int lane = threadIdx.x & 63;
    const int wave = threadIdx.x >> 6;

    float wb[16], wd[16];
#pragma unroll
    for (int f = 0; f < 16; ++f) {
        float wt  = W1[f * 64 + lane];
        float wbo = W1[(16 + f) * 64 + lane];
        wb[f] = wbo;
        wd[f] = wt - wbo;
    }
    const float bias = b1[lane];

    const int base = blockIdx.x * 64 + wave * 16;
    for (int n = 0; n < 16; ++n) {
        const int p = base + n;
        const float4* xr = (const float4*)(x + (size_t)p * 16);
        float4 a0 = xr[0], a1 = xr[1], a2 = xr[2], a3 = xr[3];
        float xv[16] = {a0.x,a0.y,a0.z,a0.w, a1.x,a1.y,a1.z,a1.w,
                        a2.x,a2.y,a2.z,a2.w, a3.x,a3.y,a3.z,a3.w};
        float uu = bias, vv = 0.f;
#pragma unroll
        for (int f = 0; f < 16; ++f) {
            uu = fmaf(xv[f], wd[f], uu);
            vv = fmaf(xv[f], wb[f], vv);
        }
        u[(size_t)p * 64 + lane] = uu;
        v[(size_t)p * 64 + lane] = vv;
    }
}

// ---------------------------------------------------------------------------
// Kernel B: kNN quarter-scan via MFMA distance tiles.
// Block = 256 threads = 4 waves = 256 queries x 256-j quarter.
// grid = G*4(qchunk)*4(jq) = 2048 -> 4 blocks/CU (LDS 38.9KB) = 4 waves/SIMD.
// Scan is BRANCHLESS: med3 chain is a no-op when d >= hp[15].
// Partial top-16 stored as packed floats (low 8 bits = local j).
// ---------------------------------------------------------------------------
__global__ __launch_bounds__(256, 4) void knn_kernel(
    const float* __restrict__ x, float* __restrict__ part)
{
    __shared__ float    DT[4][SLAB * DSTRIDE];  // 34816 B (per-wave private)
    __shared__ uint16_t zh[SLAB * 24];
    __shared__ uint16_t zl[SLAB * 24];
    __shared__ float    sqs[JLEN];              // 1 KB

    const int b      = blockIdx.x;
    const int g      = b >> 4;
    const int qchunk = (b >> 2) & 3;
    const int jq     = b & 3;
    const float* xg  = x + (size_t)g * NP_ * F_;
    const int tid  = threadIdx.x;
    const int lane = tid & 63;
    const int wave = tid >> 6;

    // --- sq_j for this block's j-quarter (exact fp32), one row per thread ---
    {
        const float4* p = (const float4*)(xg + (size_t)(jq * JLEN + tid) * 16);
        float4 a = p[0], bb = p[1], c = p[2], d = p[3];
        float s = a.x*a.x + a.y*a.y + a.z*a.z + a.w*a.w;
        s += bb.x*bb.x + bb.y*bb.y + bb.z*bb.z + bb.w*bb.w;
        s += c.x*c.x + c.y*c.y + c.z*c.z + c.w*c.w;
        s += d.x*d.x + d.y*d.y + d.z*d.z + d.w*d.w;
        sqs[tid] = s;
    }

    // --- A fragments: wave's 64 query rows, 4 row-tiles of 16 ---
    const int qbase = qchunk * 256 + wave * 64;
    const int arow  = lane & 15;
    const int agrp  = lane >> 4;
    const int aoct  = agrp & 1;
    short8v a1[4], a2[4];
#pragma unroll
    for (int rt = 0; rt < 4; ++rt) {
        const float* src = xg + (size_t)(qbase + rt * 16 + arow) * 16 + aoct * 8;
        float4 f0 = ((const float4*)src)[0];
        float4 f1 = ((const float4*)src)[1];
        float fv[8] = {f0.x,f0.y,f0.z,f0.w, f1.x,f1.y,f1.z,f1.w};
        short8v h, l;
#pragma unroll
        for (int i = 0; i < 8; ++i) {
            uint16_t hb = bf_rne(fv[i]);
            h[i] = (short)hb;
            l[i] = (short)bf_rne(fv[i] - bf_to_f(hb));
        }
        short8v zz = {0,0,0,0,0,0,0,0};
        a1[rt] = (agrp < 2) ? h : l;
        a2[rt] = (agrp < 2) ? h : zz;
    }

    float hp[16];
#pragma unroll
    for (int m = 0; m < 16; ++m) hp[m] = __uint_as_float(0x7F000000u);

    float* dtw = DT[wave];
    const int bcol  = lane & 15;
    const int bgrp4 = (lane >> 4) & 1;

#pragma unroll
    for (int sl = 0; sl < NSLABQ; ++sl) {
        __syncthreads();
        // --- stage slab rows as bf16 hi/lo (32 rows x 4 quads) ---
        if (tid < SLAB * 4) {
            const int row = tid >> 2, q4 = tid & 3;
            const float4 f = *(const float4*)(
                xg + (size_t)(jq * JLEN + sl * SLAB + row) * 16 + q4 * 4);
            uint16_t h0 = bf_rne(f.x), h1 = bf_rne(f.y), h2 = bf_rne(f.z), h3 = bf_rne(f.w);
            short4v hv = {(short)h0, (short)h1, (short)h2, (short)h3};
            short4v lv = {(short)bf_rne(f.x - bf_to_f(h0)), (short)bf_rne(f.y - bf_to_f(h1)),
                          (short)bf_rne(f.z - bf_to_f(h2)), (short)bf_rne(f.w - bf_to_f(h3))};
            *(short4v*)&zh[row * 24 + q4 * 4] = hv;
            *(short4v*)&zl[row * 24 + q4 * 4] = lv;
        }
        __syncthreads();

        // --- MFMA distance tiles + fold + transpose-store to DT ---
#pragma unroll
        for (int ct = 0; ct < SLAB / 16; ++ct) {
            short8v b1v = *(const short8v*)&zh[(ct * 16 + bcol) * 24 + bgrp4 * 8];
            short8v b2v = *(const short8v*)&zl[(ct * 16 + bcol) * 24 + bgrp4 * 8];
            const float sqv = sqs[sl * SLAB + ct * 16 + bcol];
#pragma unroll
            for (int rt = 0; rt < 4; ++rt) {
                float4v acc = {0.f, 0.f, 0.f, 0.f};
                acc = __builtin_amdgcn_mfma_f32_16x16x32_bf16(a1[rt], b1v, acc, 0, 0, 0);
                acc = __builtin_amdgcn_mfma_f32_16x16x32_bf16(a2[rt], b2v, acc, 0, 0, 0);
                float4 outv;
                outv.x = fmaf(-2.f, acc[0], sqv);
                outv.y = fmaf(-2.f, acc[1], sqv);
                outv.z = fmaf(-2.f, acc[2], sqv);
                outv.w = fmaf(-2.f, acc[3], sqv);
                *(float4*)&dtw[(ct * 16 + bcol) * DSTRIDE + rt * 16 + (lane >> 4) * 4] = outv;
            }
        }
        asm volatile("s_waitcnt lgkmcnt(0)" ::: "memory");
        __builtin_amdgcn_sched_barrier(0);

        // --- branchless scan: lane owns query (qbase+lane) ---
        const float* dtr = dtw + lane;
#pragma unroll
        for (int j = 0; j < SLAB; ++j) {
            float d = dtr[j * DSTRIDE];
            const uint32_t jl = (uint32_t)(sl * SLAB + j);   // compile-time
            float dpf = __uint_as_float(
                (__float_as_uint(d) & 0xFFFFFF00u) | jl);
#pragma unroll
            for (int m = 15; m >= 1; --m)
                hp[m] = __builtin_amdgcn_fmed3f(dpf, hp[m - 1], hp[m]);
            hp[0] = fminf(hp[0], dpf);
        }
    }

    // --- store packed partial list: part[qglobal*64 + jq*16 + m] ---
    const size_t qg = (size_t)g * NP_ + qchunk * 256 + wave * 64 + lane;
    float* dst = part + qg * 64 + jq * 16;
#pragma unroll
    for (int m4 = 0; m4 < 4; ++m4) {
        float4 o = {hp[m4*4+0], hp[m4*4+1], hp[m4*4+2], hp[m4*4+3]};
        *(float4*)(dst + m4 * 4) = o;
    }
}

// ---------------------------------------------------------------------------
// Kernel B2: merge 4 quarter-wise top-16 lists -> global top-16 per query.
// Thread per query; 64 branchless chain-inserts. Quarter id folded into
// bits 8-9 (global j = bits 0..9).
// ---------------------------------------------------------------------------
__global__ __launch_bounds__(256) void merge_kernel(
    const float* __restrict__ part, int* __restrict__ idxw)
{
    const size_t p = (size_t)blockIdx.x * 256 + threadIdx.x;
    const float* src = part + p * 64;

    float hp[16];
#pragma unroll
    for (int m = 0; m < 16; ++m) hp[m] = __uint_as_float(0x7F000000u);

#pragma unroll
    for (int qtr = 0; qtr < 4; ++qtr) {
#pragma unroll
        for (int m4 = 0; m4 < 4; ++m4) {
            float4 v = *(const float4*)(src + qtr * 16 + m4 * 4);
            float e[4] = {v.x, v.y, v.z, v.w};
#pragma unroll
            for (int t = 0; t < 4; ++t) {
                uint32_t uu = __float_as_uint(e[t]);
                float key = __uint_as_float(
                    (uu & 0xFFFFFC00u) | ((uint32_t)qtr << 8) | (uu & 0xFFu));
#pragma unroll
                for (int m = 15; m >= 1; --m)
                    hp[m] = __builtin_amdgcn_fmed3f(key, hp[m - 1], hp[m]);
                hp[0] = fminf(hp[0], key);
            }
        }
    }

    int* row = idxw + p * K_;
#pragma unroll
    for (int m = 0; m < 16; ++m)
        row[m] = (int)(__float_as_uint(hp[m]) & 1023u);
}

// ---------------------------------------------------------------------------
// Kernel C: S[g][h] = sum_{i,k} relu(u_i[h] + v_{idx[i][k]}[h])  (unchanged)
// ---------------------------------------------------------------------------
__global__ __launch_bounds__(256) void gather_kernel(
    const float* __restrict__ u, const float* __restrict__ v,
    const int* __restrict__ idxw, float* __restrict__ S)
{
    const int lane = threadIdx.x & 63;
    const int wave = threadIdx.x >> 6;
    const int pbase = blockIdx.x * 128 + wave * 32;
    const int g = pbase >> 10;
    const float* vg = v + (((size_t)g << 10) << 6);
    float acc = 0.f;
    for (int n = 0; n < 32; ++n) {
        const int ii = pbase + n;
        const float uu = u[(size_t)ii * 64 + lane];
        const int4* irow = (const int4*)(idxw + (size_t)ii * 16);
#pragma unroll
        for (int q = 0; q < 4; ++q) {
            int4 j4 = irow[q];
            float v0 = vg[(size_t)j4.x * 64 + lane];
            float v1 = vg[(size_t)j4.y * 64 + lane];
            float v2 = vg[(size_t)j4.z * 64 + lane];
            float v3 = vg[(size_t)j4.w * 64 + lane];
            acc += fmaxf(0.f, uu + v0);
            acc += fmaxf(0.f, uu + v1);
            acc += fmaxf(0.f, uu + v2);
            acc += fmaxf(0.f, uu + v3);
        }
    }
    atomicAdd(&S[(g << 6) + lane], acc);
}

// ---------------------------------------------------------------------------
// Kernel D: per-group head (unchanged).
// ---------------------------------------------------------------------------
__global__ __launch_bounds__(128) void head_kernel(
    const float* __restrict__ S, const float* __restrict__ W2,
    const float* __restrict__ b2, const float* __restrict__ Wf,
    const float* __restrict__ bf, float* __restrict__ out)
{
    __shared__ float hbar[64];
    __shared__ float t[64];
    const int g = blockIdx.x;
    const int tid = threadIdx.x;
    if (tid < 64) hbar[tid] = S[g * 64 + tid] * (1.f / (1024.f * 16.f));
    __syncthreads();
    if (tid < 64) {
        float a = b2[tid];
        for (int h = 0; h < 64; ++h) a = fmaf(hbar[h], W2[h * 64 + tid], a);
        t[tid] = a;
    }
    __syncthreads();
    float a = bf[tid];
    for (int h = 0; h < 64; ++h) a = fmaf(t[h], Wf[h * 128 + tid], a);
    out[g * 128 + tid] = a;
}

// ---------------------------------------------------------------------------
extern "C" void kernel_launch(void* const* d_in, const int* in_sizes, int n_in,
                              void* d_out, int out_size, void* d_ws, size_t ws_size,
                              hipStream_t stream)
{
    const float* x  = (const float*)d_in[0];
    const float* W1 = (const float*)d_in[2];
    const float* b1 = (const float*)d_in[3];
    const float* W2 = (const float*)d_in[4];
    const float* b2 = (const float*)d_in[5];
    const float* Wf = (const float*)d_in[6];
    const float* bf = (const float*)d_in[7];
    float* out = (float*)d_out;

    char* ws = (char*)d_ws;
    const size_t N = (size_t)G_ * NP_;               // 131072
    float* u    = (float*)ws;                        // 32 MB
    float* v    = (float*)(ws + N * 64 * 4);         // 32 MB
    int*   idxw = (int*)  (ws + 2 * N * 64 * 4);     //  8 MB
    float* S    = (float*)(ws + 2 * N * 64 * 4 + N * 16 * 4);
    float* part = u;   // aliases u: lifetime (knn->merge) ends before uv writes u

    hipMemsetAsync(S, 0, G_ * H_ * sizeof(float), stream);

    knn_kernel   <<<G_ * 16, 256, 0, stream>>>(x, part);
    merge_kernel <<<(G_ * NP_) / 256, 256, 0, stream>>>(part, idxw);
    uv_kernel    <<<2048, 256, 0, stream>>>(x, W1, b1, u, v);
    gather_kernel<<<1024, 256, 0, stream>>>(u, v, idxw, S);
    head_kernel  <<<G_, 128, 0, stream>>>(S, W2, b2, Wf, bf, out);
}

// Round 5
// 286.628 us; speedup vs baseline: 1.0050x; 1.0017x over previous
//
#include <hip/hip_runtime.h>
#include <hip/hip_bf16.h>
#include <stdint.h>

#define G_    128
#define NP_   1024
#define F_    16
#define K_    16
#define H_    64
#define L_    64
#define OUT_  128

#define SLAB    32
#define DSTRIDE 68            // floats; (4j+lane)%32 -> 2 lanes/bank (free)
#define JQ_     4             // j-range split factor
#define JLEN    (NP_ / JQ_)   // 256 j per block
#define NSLABQ  (JLEN / SLAB) // 8 slabs per block

typedef short  short8v  __attribute__((ext_vector_type(8)));
typedef short  short4v  __attribute__((ext_vector_type(4)));
typedef float  float4v  __attribute__((ext_vector_type(4)));

__device__ __forceinline__ uint16_t bf_rne(float f) {
    uint32_t u = __float_as_uint(f);
    return (uint16_t)((u + 0x7FFFu + ((u >> 16) & 1u)) >> 16);
}
__device__ __forceinline__ float bf_to_f(uint16_t h) {
    return __uint_as_float((uint32_t)h << 16);
}

// ---------------------------------------------------------------------------
// Kernel A: per-point u/v tables (unchanged).
// ---------------------------------------------------------------------------
__global__ __launch_bounds__(256) void uv_kernel(
    const float* __restrict__ x, const float* __restrict__ W1,
    const float* __restrict__ b1, float* __restrict__ u, float* __restrict__ v)
{
    const int lane = threadIdx.x & 63;
    const int wave = threadIdx.x >> 6;

    float wb[16], wd[16];
#pragma unroll
    for (int f = 0; f < 16; ++f) {
        float wt  = W1[f * 64 + lane];
        float wbo = W1[(16 + f) * 64 + lane];
        wb[f] = wbo;
        wd[f] = wt - wbo;
    }
    const float bias = b1[lane];

    const int base = blockIdx.x * 64 + wave * 16;
    for (int n = 0; n < 16; ++n) {
        const int p = base + n;
        const float4* xr = (const float4*)(x + (size_t)p * 16);
        float4 a0 = xr[0], a1 = xr[1], a2 = xr[2], a3 = xr[3];
        float xv[16] = {a0.x,a0.y,a0.z,a0.w, a1.x,a1.y,a1.z,a1.w,
                        a2.x,a2.y,a2.z,a2.w, a3.x,a3.y,a3.z,a3.w};
        float uu = bias, vv = 0.f;
#pragma unroll
        for (int f = 0; f < 16; ++f) {
            uu = fmaf(xv[f], wd[f], uu);
            vv = fmaf(xv[f], wb[f], vv);
        }
        u[(size_t)p * 64 + lane] = uu;
        v[(size_t)p * 64 + lane] = vv;
    }
}

// ---------------------------------------------------------------------------
// Kernel B: kNN quarter-scan via MFMA distance tiles.
// Block = 256 threads = 4 waves = 256 queries x 256-j quarter.
// grid = G*4(qchunk)*4(jq) = 2048 -> 4 blocks/CU (LDS 38.9KB) = 4 waves/SIMD.
// Scan is BRANCHLESS: med3 chain is a no-op when d >= hp[15].
// Partial top-16 stored as packed floats (low 8 bits = local j).
// ---------------------------------------------------------------------------
__global__ __launch_bounds__(256, 4) void knn_kernel(
    const float* __restrict__ x, float* __restrict__ part)
{
    __shared__ float    DT[4][SLAB * DSTRIDE];  // 34816 B (per-wave private)
    __shared__ uint16_t zh[SLAB * 24];
    __shared__ uint16_t zl[SLAB * 24];
    __shared__ float    sqs[JLEN];              // 1 KB

    const int b      = blockIdx.x;
    const int g      = b >> 4;
    const int qchunk = (b >> 2) & 3;
    const int jq     = b & 3;
    const float* xg  = x + (size_t)g * NP_ * F_;
    const int tid  = threadIdx.x;
    const int lane = tid & 63;
    const int wave = tid >> 6;

    // --- sq_j for this block's j-quarter (exact fp32), one row per thread ---
    {
        const float4* p = (const float4*)(xg + (size_t)(jq * JLEN + tid) * 16);
        float4 a = p[0], bb = p[1], c = p[2], d = p[3];
        float s = a.x*a.x + a.y*a.y + a.z*a.z + a.w*a.w;
        s += bb.x*bb.x + bb.y*bb.y + bb.z*bb.z + bb.w*bb.w;
        s += c.x*c.x + c.y*c.y + c.z*c.z + c.w*c.w;
        s += d.x*d.x + d.y*d.y + d.z*d.z + d.w*d.w;
        sqs[tid] = s;
    }

    // --- A fragments: wave's 64 query rows, 4 row-tiles of 16 ---
    const int qbase = qchunk * 256 + wave * 64;
    const int arow  = lane & 15;
    const int agrp  = lane >> 4;
    const int aoct  = agrp & 1;
    short8v a1[4], a2[4];
#pragma unroll
    for (int rt = 0; rt < 4; ++rt) {
        const float* src = xg + (size_t)(qbase + rt * 16 + arow) * 16 + aoct * 8;
        float4 f0 = ((const float4*)src)[0];
        float4 f1 = ((const float4*)src)[1];
        float fv[8] = {f0.x,f0.y,f0.z,f0.w, f1.x,f1.y,f1.z,f1.w};
        short8v h, l;
#pragma unroll
        for (int i = 0; i < 8; ++i) {
            uint16_t hb = bf_rne(fv[i]);
            h[i] = (short)hb;
            l[i] = (short)bf_rne(fv[i] - bf_to_f(hb));
        }
        short8v zz = {0,0,0,0,0,0,0,0};
        a1[rt] = (agrp < 2) ? h : l;
        a2[rt] = (agrp < 2) ? h : zz;
    }

    float hp[16];
#pragma unroll
    for (int m = 0; m < 16; ++m) hp[m] = __uint_as_float(0x7F000000u);

    float* dtw = DT[wave];
    const int bcol  = lane & 15;
    const int bgrp4 = (lane >> 4) & 1;

#pragma unroll
    for (int sl = 0; sl < NSLABQ; ++sl) {
        __syncthreads();
        // --- stage slab rows as bf16 hi/lo (32 rows x 4 quads) ---
        if (tid < SLAB * 4) {
            const int row = tid >> 2, q4 = tid & 3;
            const float4 f = *(const float4*)(
                xg + (size_t)(jq * JLEN + sl * SLAB + row) * 16 + q4 * 4);
            uint16_t h0 = bf_rne(f.x), h1 = bf_rne(f.y), h2 = bf_rne(f.z), h3 = bf_rne(f.w);
            short4v hv = {(short)h0, (short)h1, (short)h2, (short)h3};
            short4v lv = {(short)bf_rne(f.x - bf_to_f(h0)), (short)bf_rne(f.y - bf_to_f(h1)),
                          (short)bf_rne(f.z - bf_to_f(h2)), (short)bf_rne(f.w - bf_to_f(h3))};
            *(short4v*)&zh[row * 24 + q4 * 4] = hv;
            *(short4v*)&zl[row * 24 + q4 * 4] = lv;
        }
        __syncthreads();

        // --- MFMA distance tiles + fold + transpose-store to DT ---
#pragma unroll
        for (int ct = 0; ct < SLAB / 16; ++ct) {
            short8v b1v = *(const short8v*)&zh[(ct * 16 + bcol) * 24 + bgrp4 * 8];
            short8v b2v = *(const short8v*)&zl[(ct * 16 + bcol) * 24 + bgrp4 * 8];
            const float sqv = sqs[sl * SLAB + ct * 16 + bcol];
#pragma unroll
            for (int rt = 0; rt < 4; ++rt) {
                float4v acc = {0.f, 0.f, 0.f, 0.f};
                acc = __builtin_amdgcn_mfma_f32_16x16x32_bf16(a1[rt], b1v, acc, 0, 0, 0);
                acc = __builtin_amdgcn_mfma_f32_16x16x32_bf16(a2[rt], b2v, acc, 0, 0, 0);
                float4 outv;
                outv.x = fmaf(-2.f, acc[0], sqv);
                outv.y = fmaf(-2.f, acc[1], sqv);
                outv.z = fmaf(-2.f, acc[2], sqv);
                outv.w = fmaf(-2.f, acc[3], sqv);
                *(float4*)&dtw[(ct * 16 + bcol) * DSTRIDE + rt * 16 + (lane >> 4) * 4] = outv;
            }
        }
        asm volatile("s_waitcnt lgkmcnt(0)" ::: "memory");
        __builtin_amdgcn_sched_barrier(0);

        // --- branchless scan: lane owns query (qbase+lane) ---
        const float* dtr = dtw + lane;
#pragma unroll
        for (int j = 0; j < SLAB; ++j) {
            float d = dtr[j * DSTRIDE];
            const uint32_t jl = (uint32_t)(sl * SLAB + j);   // compile-time
            float dpf = __uint_as_float(
                (__float_as_uint(d) & 0xFFFFFF00u) | jl);
#pragma unroll
            for (int m = 15; m >= 1; --m)
                hp[m] = __builtin_amdgcn_fmed3f(dpf, hp[m - 1], hp[m]);
            hp[0] = fminf(hp[0], dpf);
        }
    }

    // --- store packed partial list: part[qglobal*64 + jq*16 + m] ---
    const size_t qg = (size_t)g * NP_ + qchunk * 256 + wave * 64 + lane;
    float* dst = part + qg * 64 + jq * 16;
#pragma unroll
    for (int m4 = 0; m4 < 4; ++m4) {
        float4 o = {hp[m4*4+0], hp[m4*4+1], hp[m4*4+2], hp[m4*4+3]};
        *(float4*)(dst + m4 * 4) = o;
    }
}

// ---------------------------------------------------------------------------
// Kernel B2: merge 4 quarter-wise top-16 lists -> global top-16 per query.
// Thread per query; 64 branchless chain-inserts. Quarter id folded into
// bits 8-9 (global j = bits 0..9).
// ---------------------------------------------------------------------------
__global__ __launch_bounds__(256) void merge_kernel(
    const float* __restrict__ part, int* __restrict__ idxw)
{
    const size_t p = (size_t)blockIdx.x * 256 + threadIdx.x;
    const float* src = part + p * 64;

    float hp[16];
#pragma unroll
    for (int m = 0; m < 16; ++m) hp[m] = __uint_as_float(0x7F000000u);

#pragma unroll
    for (int qtr = 0; qtr < 4; ++qtr) {
#pragma unroll
        for (int m4 = 0; m4 < 4; ++m4) {
            float4 v = *(const float4*)(src + qtr * 16 + m4 * 4);
            float e[4] = {v.x, v.y, v.z, v.w};
#pragma unroll
            for (int t = 0; t < 4; ++t) {
                uint32_t uu = __float_as_uint(e[t]);
                float key = __uint_as_float(
                    (uu & 0xFFFFFC00u) | ((uint32_t)qtr << 8) | (uu & 0xFFu));
#pragma unroll
                for (int m = 15; m >= 1; --m)
                    hp[m] = __builtin_amdgcn_fmed3f(key, hp[m - 1], hp[m]);
                hp[0] = fminf(hp[0], key);
            }
        }
    }

    int* row = idxw + p * K_;
#pragma unroll
    for (int m = 0; m < 16; ++m)
        row[m] = (int)(__float_as_uint(hp[m]) & 1023u);
}

// ---------------------------------------------------------------------------
// Kernel C: S[g][h] = sum_{i,k} relu(u_i[h] + v_{idx[i][k]}[h])  (unchanged)
// ---------------------------------------------------------------------------
__global__ __launch_bounds__(256) void gather_kernel(
    const float* __restrict__ u, const float* __restrict__ v,
    const int* __restrict__ idxw, float* __restrict__ S)
{
    const int lane = threadIdx.x & 63;
    const int wave = threadIdx.x >> 6;
    const int pbase = blockIdx.x * 128 + wave * 32;
    const int g = pbase >> 10;
    const float* vg = v + (((size_t)g << 10) << 6);
    float acc = 0.f;
    for (int n = 0; n < 32; ++n) {
        const int ii = pbase + n;
        const float uu = u[(size_t)ii * 64 + lane];
        const int4* irow = (const int4*)(idxw + (size_t)ii * 16);
#pragma unroll
        for (int q = 0; q < 4; ++q) {
            int4 j4 = irow[q];
            float v0 = vg[(size_t)j4.x * 64 + lane];
            float v1 = vg[(size_t)j4.y * 64 + lane];
            float v2 = vg[(size_t)j4.z * 64 + lane];
            float v3 = vg[(size_t)j4.w * 64 + lane];
            acc += fmaxf(0.f, uu + v0);
            acc += fmaxf(0.f, uu + v1);
            acc += fmaxf(0.f, uu + v2);
            acc += fmaxf(0.f, uu + v3);
        }
    }
    atomicAdd(&S[(g << 6) + lane], acc);
}

// ---------------------------------------------------------------------------
// Kernel D: per-group head (unchanged).
// ---------------------------------------------------------------------------
__global__ __launch_bounds__(128) void head_kernel(
    const float* __restrict__ S, const float* __restrict__ W2,
    const float* __restrict__ b2, const float* __restrict__ Wf,
    const float* __restrict__ bf, float* __restrict__ out)
{
    __shared__ float hbar[64];
    __shared__ float t[64];
    const int g = blockIdx.x;
    const int tid = threadIdx.x;
    if (tid < 64) hbar[tid] = S[g * 64 + tid] * (1.f / (1024.f * 16.f));
    __syncthreads();
    if (tid < 64) {
        float a = b2[tid];
        for (int h = 0; h < 64; ++h) a = fmaf(hbar[h], W2[h * 64 + tid], a);
        t[tid] = a;
    }
    __syncthreads();
    float a = bf[tid];
    for (int h = 0; h < 64; ++h) a = fmaf(t[h], Wf[h * 128 + tid], a);
    out[g * 128 + tid] = a;
}

// ---------------------------------------------------------------------------
extern "C" void kernel_launch(void* const* d_in, const int* in_sizes, int n_in,
                              void* d_out, int out_size, void* d_ws, size_t ws_size,
                              hipStream_t stream)
{
    const float* x  = (const float*)d_in[0];
    const float* W1 = (const float*)d_in[2];
    const float* b1 = (const float*)d_in[3];
    const float* W2 = (const float*)d_in[4];
    const float* b2 = (const float*)d_in[5];
    const float* Wf = (const float*)d_in[6];
    const float* bf = (const float*)d_in[7];
    float* out = (float*)d_out;

    char* ws = (char*)d_ws;
    const size_t N = (size_t)G_ * NP_;               // 131072
    float* u    = (float*)ws;                        // 32 MB
    float* v    = (float*)(ws + N * 64 * 4);         // 32 MB
    int*   idxw = (int*)  (ws + 2 * N * 64 * 4);     //  8 MB
    float* S    = (float*)(ws + 2 * N * 64 * 4 + N * 16 * 4);
    float* part = u;   // aliases u: lifetime (knn->merge) ends before uv writes u

    hipMemsetAsync(S, 0, G_ * H_ * sizeof(float), stream);

    knn_kernel   <<<G_ * 16, 256, 0, stream>>>(x, part);
    merge_kernel <<<(G_ * NP_) / 256, 256, 0, stream>>>(part, idxw);
    uv_kernel    <<<2048, 256, 0, stream>>>(x, W1, b1, u, v);
    gather_kernel<<<1024, 256, 0, stream>>>(u, v, idxw, S);
    head_kernel  <<<G_, 128, 0, stream>>>(S, W2, b2, Wf, bf, out);
}